// Round 10
// baseline (112.658 us; speedup 1.0000x reference)
//
#include <hip/hip_runtime.h>

#define L_SEQ 1024
#define CM    256
#define CZ    128
#define NAA   21
#define NPAIR (NAA * NAA)            // 441
#define ROWB  (CZ * 4)               // 512 B per channel-row
#define TBL_BYTES (3 * NPAIR * ROWB) // 677,376 B in d_ws

typedef float f32x4 __attribute__((ext_vector_type(4)));

static __device__ __forceinline__ int clip21(int s) {
    return s < 0 ? 0 : (s > 20 ? 20 : s);
}

// ---- kernel 1: build the 3*441 distinct pair rows into ws ----
// ws layout: [0]      Tc  [si*21+sj][c] = (Wl[si]+bl)+(Wr[sj]+br)
//            [441*CZ] Tlo = Tc + rel[0]      (d==0 saturated)
//            [882*CZ] Thi = Tc + rel[64]     (d==64 saturated)
__global__ __launch_bounds__(128) void build_tables(
    const int*   __restrict__ seq,
    const float* __restrict__ Wl,  const float* __restrict__ bl,
    const float* __restrict__ Wr,  const float* __restrict__ br,
    const float* __restrict__ rel,
    float* __restrict__ ws)
{
    const int bx = blockIdx.x;           // 0..440
    const int si = bx / NAA;
    const int sj = bx - si * NAA;
    const int c  = threadIdx.x;          // 0..127
    (void)seq;
    const float cmb = (Wl[si * CZ + c] + bl[c]) + (Wr[sj * CZ + c] + br[c]);
    ws[bx * CZ + c]                 = cmb;
    ws[NPAIR * CZ + bx * CZ + c]    = cmb + rel[c];
    ws[2 * NPAIR * CZ + bx * CZ + c] = cmb + rel[64 * CZ + c];
}

// ---- kernel 2: pure streaming (no table prologue, nt stores) ----
__global__ __launch_bounds__(256, 6) void stream_pair(
    const int*   __restrict__ seq,
    const int*   __restrict__ ri,
    const float* __restrict__ Wm,  const float* __restrict__ bm,
    const float* __restrict__ rel,
    const float* __restrict__ ws,
    float* __restrict__ out_msa,    // [L, CM]
    float* __restrict__ out_pair)   // [L, L, CZ]
{
    __shared__ unsigned sd[512];   // per-j key: saturated -> table byte offset;
                                   // mid -> 0x80000000 | (si*21+sj) | (d<<9)
    const int tid = threadIdx.x;
    const int bx  = blockIdx.x;
    const int i   = bx >> 1;
    const int j0  = (bx & 1) * 512;

    const int s_i  = clip21(seq[i]);
    const int rii  = ri[i];
    const int si21 = s_i * NAA;

    for (int jj = tid; jj < 512; jj += 256) {
        const int j  = j0 + jj;
        const int sj = clip21(seq[j]);
        int d = rii - ri[j] + 32;
        d = d < 0 ? 0 : (d > 64 ? 64 : d);
        const unsigned pr = (unsigned)(si21 + sj);
        sd[jj] = (d == 0)  ? (NPAIR + pr) * ROWB
               : (d == 64) ? (2u * NPAIR + pr) * ROWB
               : (0x80000000u | pr | ((unsigned)d << 9));
    }
    __syncthreads();

    // msa row i (chunk-0 blocks): gather + bias, exact
    if ((bx & 1) == 0)
        out_msa[i * CM + tid] = Wm[s_i * CM + tid] + bm[tid];

    const int cl = tid & 31;         // channel group (16 B each)
    const int jo = tid >> 5;         // 0..7
    const int cb = cl * 16;
    const char* wsb  = (const char*)ws;
    const char* relb = (const char*)rel;

    char* outp = (char*)(out_pair + ((size_t)i * L_SEQ + j0 + jo) * CZ) + cb;

    #pragma unroll 8
    for (int it = 0; it < 64; ++it) {
        const unsigned p = sd[it * 8 + jo];
        f32x4 v;
        if (!(p & 0x80000000u)) {
            v = *(const f32x4*)(wsb + p + cb);                          // L2 hit
        } else {
            const f32x4 a = *(const f32x4*)(wsb + (p & 0x1FFu) * ROWB + cb);
            const f32x4 r = *(const f32x4*)(relb + ((p >> 9) & 0x7Fu) * ROWB + cb);
            v = a + r;   // elementwise fadd, same order as reference
        }
        __builtin_nontemporal_store(v, (f32x4*)outp);
        outp += 8 * ROWB;
    }
}

// ---- fallback (R7 structure) if ws is too small ----
__global__ __launch_bounds__(256, 4) void fallback_kernel(
    const int*   __restrict__ seq,
    const int*   __restrict__ ri,
    const float* __restrict__ Wm,  const float* __restrict__ bm,
    const float* __restrict__ Wl,  const float* __restrict__ bl,
    const float* __restrict__ Wr,  const float* __restrict__ br,
    const float* __restrict__ rel,
    float* __restrict__ out_msa,
    float* __restrict__ out_pair)
{
    __shared__ float comb   [NAA * CZ];
    __shared__ float comb_lo[NAA * CZ];
    __shared__ float comb_hi[NAA * CZ];
    __shared__ unsigned int sd[512];

    const int tid = threadIdx.x;
    const int bx  = blockIdx.x;
    const int i   = bx >> 1;
    const int j0  = (bx & 1) * 512;

    const int s_i = clip21(seq[i]);
    const int rii = ri[i];

    for (int jj = tid; jj < 512; jj += 256) {
        const int j = j0 + jj;
        const int sj = clip21(seq[j]);
        int d = rii - ri[j] + 32;
        d = d < 0 ? 0 : (d > 64 ? 64 : d);
        sd[jj] = (unsigned)(sj * 512) | ((unsigned)(d * 512) << 16);
    }
    for (int idx = tid; idx < NAA * CZ; idx += 256) {
        const int c = idx & (CZ - 1);
        const float cmb = (Wl[s_i * CZ + c] + bl[c]) + (Wr[idx] + br[c]);
        comb[idx]    = cmb;
        comb_lo[idx] = cmb + rel[c];
        comb_hi[idx] = cmb + rel[64 * CZ + c];
    }
    __syncthreads();

    if ((bx & 1) == 0)
        out_msa[i * CM + tid] = Wm[s_i * CM + tid] + bm[tid];

    const int cb = (tid & 31) * 16;
    const int jo = tid >> 5;
    const char* rel_b     = (const char*)rel;
    const char* comb_b    = (const char*)comb;
    const char* comb_lo_b = (const char*)comb_lo;
    const char* comb_hi_b = (const char*)comb_hi;
    const int lo_thresh = i + 32;
    const int hi_thresh = i - 32 - 7;

    float* outp = out_pair + ((size_t)i * L_SEQ + j0 + jo) * CZ + (cb >> 2);

    #pragma unroll 4
    for (int it = 0; it < 64; ++it) {
        const int jg = j0 + it * 8;
        const unsigned int p   = sd[it * 8 + jo];
        const unsigned int row = p & 0xFFFFu;
        const bool is_lo = (jg >= lo_thresh);
        const bool is_hi = (jg <= hi_thresh);
        const char* base = is_lo ? comb_lo_b : (is_hi ? comb_hi_b : comb_b);
        float4 v = *(const float4*)(base + row + cb);
        if (!(is_lo || is_hi)) {
            const float4 rv = *(const float4*)(rel_b + (p >> 16) + cb);
            v.x += rv.x; v.y += rv.y; v.z += rv.z; v.w += rv.w;
        }
        *(float4*)outp = v;
        outp += 8 * CZ;
    }
}

extern "C" void kernel_launch(void* const* d_in, const int* in_sizes, int n_in,
                              void* d_out, int out_size, void* d_ws, size_t ws_size,
                              hipStream_t stream) {
    const int*   seq = (const int*)d_in[0];
    const int*   ri  = (const int*)d_in[1];
    const float* Wm  = (const float*)d_in[2];
    const float* bm  = (const float*)d_in[3];
    const float* Wl  = (const float*)d_in[4];
    const float* bl  = (const float*)d_in[5];
    const float* Wr  = (const float*)d_in[6];
    const float* br  = (const float*)d_in[7];
    const float* rel = (const float*)d_in[8];

    float* out      = (float*)d_out;
    float* out_msa  = out;                          // L*CM f32
    float* out_pair = out + (size_t)L_SEQ * CM;     // L*L*CZ f32

    if (ws_size >= (size_t)TBL_BYTES) {
        float* ws = (float*)d_ws;
        hipLaunchKernelGGL(build_tables, dim3(NPAIR), dim3(CZ), 0, stream,
                           seq, Wl, bl, Wr, br, rel, ws);
        hipLaunchKernelGGL(stream_pair, dim3(L_SEQ * 2), dim3(256), 0, stream,
                           seq, ri, Wm, bm, rel, ws, out_msa, out_pair);
    } else {
        hipLaunchKernelGGL(fallback_kernel, dim3(L_SEQ * 2), dim3(256), 0, stream,
                           seq, ri, Wm, bm, Wl, bl, Wr, br, rel, out_msa, out_pair);
    }
}

// Round 11
// 108.437 us; speedup vs baseline: 1.0389x; 1.0389x over previous
//
#include <hip/hip_runtime.h>

#define L_SEQ 1024
#define CM    256
#define CZ    128
#define NAA   21
#define NPAIR (NAA * NAA)            // 441
#define ROWB  (CZ * 4)               // 512 B per channel-row
#define TBL_BYTES (3 * NPAIR * ROWB) // 677,376 B in d_ws
#define PAIR_TILES (L_SEQ * 16)      // 16384 tiles of 64 j's (32 KB each)
#define MSA_TILES  32                // 32 tiles x 32 KB = 1 MB msa

typedef float f32x4 __attribute__((ext_vector_type(4)));

static __device__ __forceinline__ int clip21(int s) {
    return s < 0 ? 0 : (s > 20 ? 20 : s);
}

// ---- kernel 1: build the 3*441 distinct pair rows into ws ----
// ws layout: [0]        Tc [si*21+sj][c] = (Wl[si]+bl)+(Wr[sj]+br)
//            [441*CZ]   Tlo = Tc + rel[0]   (d==0 saturated)
//            [882*CZ]   Thi = Tc + rel[64]  (d==64 saturated)
__global__ __launch_bounds__(128) void build_tables(
    const float* __restrict__ Wl,  const float* __restrict__ bl,
    const float* __restrict__ Wr,  const float* __restrict__ br,
    const float* __restrict__ rel,
    float* __restrict__ ws)
{
    const int bx = blockIdx.x;           // 0..440
    const int si = bx / NAA;
    const int sj = bx - si * NAA;
    const int c  = threadIdx.x;          // 0..127
    const float cmb = (Wl[si * CZ + c] + bl[c]) + (Wr[sj * CZ + c] + br[c]);
    ws[bx * CZ + c]                  = cmb;
    ws[NPAIR * CZ + bx * CZ + c]     = cmb + rel[c];
    ws[2 * NPAIR * CZ + bx * CZ + c] = cmb + rel[64 * CZ + c];
}

// ---- kernel 2: pure streaming sweep, 32 KB tiles, 0 LDS, no barrier ----
__global__ __launch_bounds__(256, 8) void stream_pair(
    const int*   __restrict__ seq,
    const int*   __restrict__ ri,
    const float* __restrict__ Wm,  const float* __restrict__ bm,
    const float* __restrict__ rel,
    const float* __restrict__ ws,
    float* __restrict__ out_msa,    // [L, CM]
    float* __restrict__ out_pair)   // [L, L, CZ]
{
    const int tid = threadIdx.x;
    const int bx  = blockIdx.x;

    if (bx < PAIR_TILES) {
        const int i  = bx >> 4;              // row
        const int j0 = (bx & 15) * 64;       // 64-j tile

        const int si21 = clip21(seq[i]) * NAA;   // uniform -> scalar
        const int rii  = ri[i];

        const int cl = tid & 31;             // channel group (16 B)
        const int jo = tid >> 5;             // 0..7
        const int cb = cl * 16;
        const char* wsb  = (const char*)ws;
        const char* relb = (const char*)rel;

        char* outp = (char*)out_pair + ((size_t)i * L_SEQ + j0 + jo) * ROWB + cb;

        #pragma unroll 8
        for (int p = 0; p < 8; ++p) {
            const int j  = j0 + p * 8 + jo;
            const int sj = clip21(seq[j]);
            int d = rii - ri[j] + 32;
            d = d < 0 ? 0 : (d > 64 ? 64 : d);
            const unsigned pr = (unsigned)(si21 + sj);

            // branchless table select: lo / hi / comb
            const unsigned off = (d == 0)  ? (NPAIR + pr) * ROWB
                               : (d == 64) ? (2u * NPAIR + pr) * ROWB
                                           : pr * ROWB;
            f32x4 v = *(const f32x4*)(wsb + off + cb);
            if (d != 0 && d != 64) {                      // rare mid band
                const f32x4 r = *(const f32x4*)(relb + (unsigned)d * ROWB + cb);
                v = v + r;
            }
            *(f32x4*)outp = v;
            outp += 8 * ROWB;
        }
    } else {
        // msa tiles: out_msa[e] = Wm[seq[e>>8]*CM + (e&255)] + bm[e&255]
        const int m = bx - PAIR_TILES;       // 0..31
        #pragma unroll 8
        for (int p = 0; p < 8; ++p) {
            const int e   = m * 8192 + p * 1024 + tid * 4;
            const int row = e >> 8;
            const int col = e & 255;
            const int s   = clip21(seq[row]);
            const f32x4 w = *(const f32x4*)(Wm + s * CM + col);
            const f32x4 b = *(const f32x4*)(bm + col);
            *(f32x4*)(out_msa + e) = w + b;
        }
    }
}

// ---- fallback (R7 structure, proven 103.5 us) if ws too small ----
__global__ __launch_bounds__(256, 4) void fallback_kernel(
    const int*   __restrict__ seq,
    const int*   __restrict__ ri,
    const float* __restrict__ Wm,  const float* __restrict__ bm,
    const float* __restrict__ Wl,  const float* __restrict__ bl,
    const float* __restrict__ Wr,  const float* __restrict__ br,
    const float* __restrict__ rel,
    float* __restrict__ out_msa,
    float* __restrict__ out_pair)
{
    __shared__ float comb   [NAA * CZ];
    __shared__ float comb_lo[NAA * CZ];
    __shared__ float comb_hi[NAA * CZ];
    __shared__ unsigned int sd[512];

    const int tid = threadIdx.x;
    const int bx  = blockIdx.x;
    const int i   = bx >> 1;
    const int j0  = (bx & 1) * 512;

    const int s_i = clip21(seq[i]);
    const int rii = ri[i];

    for (int jj = tid; jj < 512; jj += 256) {
        const int j = j0 + jj;
        const int sj = clip21(seq[j]);
        int d = rii - ri[j] + 32;
        d = d < 0 ? 0 : (d > 64 ? 64 : d);
        sd[jj] = (unsigned)(sj * 512) | ((unsigned)(d * 512) << 16);
    }
    for (int idx = tid; idx < NAA * CZ; idx += 256) {
        const int c = idx & (CZ - 1);
        const float cmb = (Wl[s_i * CZ + c] + bl[c]) + (Wr[idx] + br[c]);
        comb[idx]    = cmb;
        comb_lo[idx] = cmb + rel[c];
        comb_hi[idx] = cmb + rel[64 * CZ + c];
    }
    __syncthreads();

    if ((bx & 1) == 0)
        out_msa[i * CM + tid] = Wm[s_i * CM + tid] + bm[tid];

    const int cb = (tid & 31) * 16;
    const int jo = tid >> 5;
    const char* rel_b     = (const char*)rel;
    const char* comb_b    = (const char*)comb;
    const char* comb_lo_b = (const char*)comb_lo;
    const char* comb_hi_b = (const char*)comb_hi;
    const int lo_thresh = i + 32;
    const int hi_thresh = i - 32 - 7;

    float* outp = out_pair + ((size_t)i * L_SEQ + j0 + jo) * CZ + (cb >> 2);

    #pragma unroll 4
    for (int it = 0; it < 64; ++it) {
        const int jg = j0 + it * 8;
        const unsigned int p   = sd[it * 8 + jo];
        const unsigned int row = p & 0xFFFFu;
        const bool is_lo = (jg >= lo_thresh);
        const bool is_hi = (jg <= hi_thresh);
        const char* base = is_lo ? comb_lo_b : (is_hi ? comb_hi_b : comb_b);
        float4 v = *(const float4*)(base + row + cb);
        if (!(is_lo || is_hi)) {
            const float4 rv = *(const float4*)(rel_b + (p >> 16) + cb);
            v.x += rv.x; v.y += rv.y; v.z += rv.z; v.w += rv.w;
        }
        *(float4*)outp = v;
        outp += 8 * CZ;
    }
}

extern "C" void kernel_launch(void* const* d_in, const int* in_sizes, int n_in,
                              void* d_out, int out_size, void* d_ws, size_t ws_size,
                              hipStream_t stream) {
    const int*   seq = (const int*)d_in[0];
    const int*   ri  = (const int*)d_in[1];
    const float* Wm  = (const float*)d_in[2];
    const float* bm  = (const float*)d_in[3];
    const float* Wl  = (const float*)d_in[4];
    const float* bl  = (const float*)d_in[5];
    const float* Wr  = (const float*)d_in[6];
    const float* br  = (const float*)d_in[7];
    const float* rel = (const float*)d_in[8];

    float* out      = (float*)d_out;
    float* out_msa  = out;                          // L*CM f32
    float* out_pair = out + (size_t)L_SEQ * CM;     // L*L*CZ f32

    if (ws_size >= (size_t)TBL_BYTES) {
        float* ws = (float*)d_ws;
        hipLaunchKernelGGL(build_tables, dim3(NPAIR), dim3(CZ), 0, stream,
                           Wl, bl, Wr, br, rel, ws);
        hipLaunchKernelGGL(stream_pair, dim3(PAIR_TILES + MSA_TILES), dim3(256), 0, stream,
                           seq, ri, Wm, bm, rel, ws, out_msa, out_pair);
    } else {
        hipLaunchKernelGGL(fallback_kernel, dim3(L_SEQ * 2), dim3(256), 0, stream,
                           seq, ri, Wm, bm, Wl, bl, Wr, br, rel, out_msa, out_pair);
    }
}

// Round 12
// 104.088 us; speedup vs baseline: 1.0823x; 1.0418x over previous
//
#include <hip/hip_runtime.h>

#define L_SEQ 1024
#define CM    256
#define CZ    128
#define NAA   21
#define CHUNK 512
#define NGRP  (CHUNK / 8)
#define PAIR_BLOCKS (L_SEQ * 2)
#define MSA_BLOCKS  32

typedef float f32x4 __attribute__((ext_vector_type(4)));

static __device__ __forceinline__ int clip21(int s) {
    return s < 0 ? 0 : (s > 20 ? 20 : s);
}

__global__ __launch_bounds__(256, 4) void InputEmbedding_kernel(
    const int*   __restrict__ seq,
    const int*   __restrict__ ri,
    const float* __restrict__ Wm,  const float* __restrict__ bm,
    const float* __restrict__ Wl,  const float* __restrict__ bl,
    const float* __restrict__ Wr,  const float* __restrict__ br,
    const float* __restrict__ rel,
    float* __restrict__ out_msa,    // [L, CM]
    float* __restrict__ out_pair)   // [L, L, CZ]
{
    const int tid = threadIdx.x;
    const int bx  = blockIdx.x;

    if (bx >= PAIR_BLOCKS) {
        // msa blocks: out_msa[e] = Wm[seq[e>>8]*CM + (e&255)] + bm[e&255]
        const int m = bx - PAIR_BLOCKS;      // 0..31
        #pragma unroll 8
        for (int p = 0; p < 8; ++p) {
            const int e   = m * 8192 + p * 1024 + tid * 4;
            const int row = e >> 8;
            const int col = e & 255;
            const int s   = clip21(seq[row]);
            const f32x4 w = *(const f32x4*)(Wm + s * CM + col);
            const f32x4 b = *(const f32x4*)(bm + col);
            *(f32x4*)(out_msa + e) = w + b;
        }
        return;
    }

    // comb    = (left[si]+bl) + (right[aa]+br)   (exact reference f32 order)
    // comb_lo = comb + rel[0]   (d==0  saturated: j >= i+32)
    // comb_hi = comb + rel[64]  (d==64 saturated: j <= i-32)
    __shared__ float comb   [NAA * CZ];
    __shared__ float comb_lo[NAA * CZ];
    __shared__ float comb_hi[NAA * CZ];
    __shared__ unsigned int sd[CHUNK];   // (sj*512) | (d*512 << 16) byte offsets

    const int i   = bx >> 1;                 // row
    const int j0  = (bx & 1) * CHUNK;        // column chunk start

    const int s_i = clip21(seq[i]);
    const int rii = ri[i];

    for (int jj = tid; jj < CHUNK; jj += 256) {
        const int j = j0 + jj;
        const int sj = clip21(seq[j]);
        int d = rii - ri[j] + 32;
        d = d < 0 ? 0 : (d > 64 ? 64 : d);
        sd[jj] = (unsigned)(sj * 512) | ((unsigned)(d * 512) << 16);
    }
    for (int idx = tid; idx < NAA * CZ; idx += 256) {
        const int c = idx & (CZ - 1);
        const float cmb = (Wl[s_i * CZ + c] + bl[c]) + (Wr[idx] + br[c]);
        comb[idx]    = cmb;
        comb_lo[idx] = cmb + rel[c];            // rel row 0
        comb_hi[idx] = cmb + rel[64 * CZ + c];  // rel row 64
    }
    __syncthreads();

    const int cb = (tid & 31) * 16;  // byte offset of this thread's float4 in a row
    const int jo = tid >> 5;         // 0..7
    const char* rel_b     = (const char*)rel;
    const char* comb_b    = (const char*)comb;
    const char* comb_lo_b = (const char*)comb_lo;
    const char* comb_hi_b = (const char*)comb_hi;

    const int lo_thresh = i + 32;        // jg >= i+32  -> all 8 j's have d=0
    const int hi_thresh = i - 32 - 7;    // jg <= i-39  -> all 8 j's have d=64

    float* outp = out_pair + ((size_t)i * L_SEQ + j0 + jo) * CZ + (cb >> 2);

    #pragma unroll 8
    for (int it = 0; it < NGRP; ++it) {
        const int jg = j0 + it * 8;
        const unsigned int p   = sd[it * 8 + jo];
        const unsigned int row = p & 0xFFFFu;

        const bool is_lo = (jg >= lo_thresh);
        const bool is_hi = (jg <= hi_thresh);

        // branchless table-pointer select; one LDS b128 read on the hot path
        const char* base = is_lo ? comb_lo_b : (is_hi ? comb_hi_b : comb_b);
        float4 v = *(const float4*)(base + row + cb);

        if (!(is_lo || is_hi)) {  // wave-uniform, ~9/64 groups per chunk
            const float4 rv = *(const float4*)(rel_b + (p >> 16) + cb);
            v.x += rv.x; v.y += rv.y; v.z += rv.z; v.w += rv.w;
        }
        *(float4*)outp = v;
        outp += 8 * CZ;
    }
}

extern "C" void kernel_launch(void* const* d_in, const int* in_sizes, int n_in,
                              void* d_out, int out_size, void* d_ws, size_t ws_size,
                              hipStream_t stream) {
    const int*   seq = (const int*)d_in[0];
    const int*   ri  = (const int*)d_in[1];
    const float* Wm  = (const float*)d_in[2];
    const float* bm  = (const float*)d_in[3];
    const float* Wl  = (const float*)d_in[4];
    const float* bl  = (const float*)d_in[5];
    const float* Wr  = (const float*)d_in[6];
    const float* br  = (const float*)d_in[7];
    const float* rel = (const float*)d_in[8];

    float* out      = (float*)d_out;
    float* out_msa  = out;                          // L*CM f32
    float* out_pair = out + (size_t)L_SEQ * CM;     // L*L*CZ f32

    hipLaunchKernelGGL(InputEmbedding_kernel, dim3(PAIR_BLOCKS + MSA_BLOCKS), dim3(256), 0, stream,
                       seq, ri, Wm, bm, Wl, bl, Wr, br, rel, out_msa, out_pair);
}